// Round 22
// baseline (476.032 us; speedup 1.0000x reference)
//
#include <hip/hip_runtime.h>
#include <hip/hip_fp8.h>

// AttnBlock2D: GroupNorm -> fused QKV -> 1-head attention (hw=4096, dh=512) -> proj + residual
// R22 = R21 (453.0us) + gemm_s8 reshaped 256x128 -> 256x256 (8 waves as 2Mx4N, wave=128x64,
//       acc[8][4]): per-K-tile MFMA density doubles (64 MFMA vs 24 ds_read vs 4 stage loads),
//       staged bytes 805->537MB. Same dbuf skeleton + swizzle. (Same lever that fixed pv8
//       in R19.) Everything else unchanged.

#define BATCH 8
#define CCH 512
#define HWP 4096
#define NG 32

#define AS1 __attribute__((address_space(1)))
#define AS3 __attribute__((address_space(3)))

typedef __attribute__((ext_vector_type(8))) short s16x8;
typedef __attribute__((ext_vector_type(4))) float f32x4;

__device__ __forceinline__ unsigned short f2bf(float f) {
  union { float f; unsigned u; } v; v.f = f;
  return (unsigned short)((v.u + 0x7FFFu + ((v.u >> 16) & 1u)) >> 16);
}
__device__ __forceinline__ unsigned char f2fp8(float f) {
  __hip_fp8_e4m3 h(f);                               // OCP e4m3, RNE+sat (fallback path)
  return (unsigned char)h.__x;
}
// pack 4 floats -> 4 fp8 bytes (v0 in byte0); clamp to +-448 (e4m3 max) BEFORE HW convert
__device__ __forceinline__ float sat8(float v) {
  return fminf(fmaxf(v, -448.f), 448.f);
}
__device__ __forceinline__ unsigned pk4_fp8(float v0, float v1, float v2, float v3) {
#if __has_builtin(__builtin_amdgcn_cvt_pk_fp8_f32)
  int pk = __builtin_amdgcn_cvt_pk_fp8_f32(sat8(v0), sat8(v1), 0, false);   // bytes 0,1
  pk = __builtin_amdgcn_cvt_pk_fp8_f32(sat8(v2), sat8(v3), pk, true);       // bytes 2,3
  return (unsigned)pk;
#else
  return (unsigned)f2fp8(v0) | ((unsigned)f2fp8(v1) << 8) |
         ((unsigned)f2fp8(v2) << 16) | ((unsigned)f2fp8(v3) << 24);
#endif
}
__device__ __forceinline__ int swz8(int r) {         // fp8 chunk swizzle
  return (r ^ (r >> 2)) & 3;
}

// ---------------- weight convert f32 -> bf16 (4 matrices) + qkv bias concat ----------------
__global__ void cvt_w(const float* __restrict__ w0, const float* __restrict__ w1,
                      const float* __restrict__ w2, const float* __restrict__ w3,
                      const float* __restrict__ bq, const float* __restrict__ bk,
                      const float* __restrict__ bv,
                      unsigned short* __restrict__ out, float* __restrict__ bcat) {
  int i = blockIdx.x * 256 + threadIdx.x;
  const int n = CCH * CCH;
  if (i < CCH) {
    bcat[i]           = bq[i];
    bcat[CCH + i]     = bk[i];
    bcat[2 * CCH + i] = bv[i];
  }
  if (i < n) {
    out[i]         = f2bf(w0[i]);
    out[n + i]     = f2bf(w1[i]);
    out[2 * n + i] = f2bf(w2[i]);
    out[3 * n + i] = f2bf(w3[i]);
  }
}

// ---------------- GroupNorm stats: one block per (b,g) ----------------
__global__ void gn_stats(const float* __restrict__ x, float* __restrict__ stats) {
  const int bg = blockIdx.x;
  const float* base = x + (size_t)bg * (16 * HWP);
  float s = 0.f, sq = 0.f;
  for (int i = threadIdx.x; i < 16 * HWP / 4; i += 256) {
    float4 v = ((const float4*)base)[i];
    s += v.x + v.y + v.z + v.w;
    sq += v.x * v.x + v.y * v.y + v.z * v.z + v.w * v.w;
  }
  #pragma unroll
  for (int o = 32; o; o >>= 1) { s += __shfl_xor(s, o); sq += __shfl_xor(sq, o); }
  __shared__ float ls[4], lq[4];
  const int wv = threadIdx.x >> 6;
  if ((threadIdx.x & 63) == 0) { ls[wv] = s; lq[wv] = sq; }
  __syncthreads();
  if (threadIdx.x == 0) {
    s = ls[0] + ls[1] + ls[2] + ls[3];
    sq = lq[0] + lq[1] + lq[2] + lq[3];
    const float inv_n = 1.f / (16.f * HWP);
    float mean = s * inv_n;
    float var = sq * inv_n - mean * mean;
    stats[2 * bg] = mean;
    stats[2 * bg + 1] = rsqrtf(var + 1e-5f);
  }
}

// ---------------- GroupNorm apply + transpose -> h_t (hw, c) bf16 ----------------
__global__ void gn_apply(const float* __restrict__ x, const float* __restrict__ stats,
                         const float* __restrict__ scale, const float* __restrict__ bias,
                         unsigned short* __restrict__ ht) {
  const int p0 = blockIdx.x * 64, c0 = blockIdx.y * 64, b = blockIdx.z;
  const int tx = threadIdx.x & 63, ty = threadIdx.x >> 6;
  __shared__ unsigned short tile[64][65];
  #pragma unroll 4
  for (int j = 0; j < 16; ++j) {
    int cl = ty + j * 4;
    int c = c0 + cl;
    int g = c >> 4;
    float mean = stats[(b * NG + g) * 2];
    float rstd = stats[(b * NG + g) * 2 + 1];
    float v = x[((size_t)(b * CCH + c)) * HWP + p0 + tx];
    v = (v - mean) * rstd * scale[c] + bias[c];
    tile[cl][tx] = f2bf(v);
  }
  __syncthreads();
  #pragma unroll 4
  for (int j = 0; j < 16; ++j) {
    int pl = ty + j * 4;
    ht[((size_t)b * HWP + p0 + pl) * CCH + c0 + tx] = tile[tx][pl];
  }
}

// ---------------- NT GEMM (R3 engine): 128x128, BK=64, dbuf, bf16 MFMA ----------------
// MODE 0: fp8 out. n0<1024: Q/K -> qk8 (ldc=1024B rows). n0>=1024: V -> byte-LDS-bounce
//         transpose -> vT8 (=Res, stride sRes bytes).   (fused QKV + V^T, all fp8)
// MODE 3: f32 out, + biasRow + Res(prefetched to regs), coalesced epilogue (final proj)
template<int MODE>
__device__ __forceinline__ void gemm_body(
    const unsigned short* __restrict__ A, const unsigned short* __restrict__ Bm,
    void* __restrict__ Cm, const float* __restrict__ biasRow,
    const float* __restrict__ biasCol, const float* __restrict__ Res,
    int K, int lda, int ldb, int ldc, float scale,
    long long sA, long long sB, long long sC, long long sRes) {
  // --- bijective XCD swizzle ---
  const int nbx = gridDim.x, nby = gridDim.y;
  const int nb = nbx * nby * gridDim.z;
  int lin = (blockIdx.z * nby + blockIdx.y) * nbx + blockIdx.x;
  int bx, by, bz;
  if ((nb & 7) == 0) {
    int logical = (lin & 7) * (nb >> 3) + (lin >> 3);
    bx = logical % nbx;
    int t = logical / nbx;
    by = t % nby;
    bz = t / nby;
  } else { bx = blockIdx.x; by = blockIdx.y; bz = blockIdx.z; }

  const unsigned short* Ab = A + (size_t)bz * sA;
  const unsigned short* Bb = Bm + (size_t)bz * sB;
  const int m0 = by * 128, n0 = bx * 128;
  __shared__ __align__(16) unsigned short sm[2][2][128 * 64];  // [A/B][dbuf][tile]
  const int tid = threadIdx.x, wave = tid >> 6, lane = tid & 63;
  const int wr = (wave >> 1) * 64, wc = (wave & 1) * 64;
  const int lr = lane & 15, lkc = lane >> 4;
  f32x4 acc[4][4] = {};

  // MODE 3: prefetch the residual tile into registers (read hides under the K-loop)
  float4 xr[16];
  if (MODE == 3) {
    #pragma unroll
    for (int pass = 0; pass < 2; ++pass)
      #pragma unroll
      for (int i = 0; i < 8; ++i) {
        int idx = i * 256 + tid;
        int rrow = idx >> 5, c4 = (idx & 31) << 2;
        size_t gidx = (size_t)(m0 + pass * 64 + rrow) * ldc + (n0 + c4);
        xr[pass * 8 + i] = *(const float4*)&Res[(size_t)bz * sRes + gidx];
      }
  }

  const int chunkBase = wave * 64 + lane;
  int srow[4], sc8[4];
  #pragma unroll
  for (int it = 0; it < 4; ++it) {
    int chunk = it * 256 + chunkBase;
    srow[it] = chunk >> 3;
    sc8[it] = (((chunk & 7) ^ (srow[it] & 7)) * 8);
  }

  #define STAGE(buf, kt)                                                                 \
    { _Pragma("unroll")                                                                  \
      for (int it = 0; it < 4; ++it) {                                                   \
        __builtin_amdgcn_global_load_lds(                                                \
            (const AS1 unsigned int*)(Ab + (size_t)(m0 + srow[it]) * lda + (kt) + sc8[it]), \
            (AS3 unsigned int*)(&sm[0][buf][0] + (size_t)(it * 256 + wave * 64) * 8), 16, 0, 0); \
        __builtin_amdgcn_global_load_lds(                                                \
            (const AS1 unsigned int*)(Bb + (size_t)(n0 + srow[it]) * ldb + (kt) + sc8[it]), \
            (AS3 unsigned int*)(&sm[1][buf][0] + (size_t)(it * 256 + wave * 64) * 8), 16, 0, 0); \
      }                                                                                  \
    }

  STAGE(0, 0);
  __syncthreads();
  int cur = 0;
  for (int kt = 0; kt < K; kt += 64) {
    if (kt + 64 < K) STAGE(cur ^ 1, kt + 64);
    #pragma unroll
    for (int kk = 0; kk < 64; kk += 32) {
      const int jbase = (kk >> 3) + lkc;
      s16x8 af[4], bfv[4];
      #pragma unroll
      for (int m = 0; m < 4; ++m) {
        int r = wr + m * 16 + lr;
        af[m] = *(const s16x8*)&sm[0][cur][r * 64 + ((jbase ^ (r & 7)) << 3)];
      }
      #pragma unroll
      for (int n = 0; n < 4; ++n) {
        int r = wc + n * 16 + lr;
        bfv[n] = *(const s16x8*)&sm[1][cur][r * 64 + ((jbase ^ (r & 7)) << 3)];
      }
      #pragma unroll
      for (int m = 0; m < 4; ++m)
        #pragma unroll
        for (int n = 0; n < 4; ++n)
          acc[m][n] = __builtin_amdgcn_mfma_f32_16x16x32_bf16(af[m], bfv[n], acc[m][n], 0, 0, 0);
    }
    __syncthreads();
    cur ^= 1;
  }
  #undef STAGE

  const int r0 = (lane >> 4) * 4, ccol = lane & 15;
  if (MODE == 0) {
    if (n0 >= 1024) {
      // ---- V-block: fp8 transpose via byte LDS bounce [128][136] -> vT8 (b,c,p) ----
      unsigned char* ltb = (unsigned char*)&sm[0][0][0];  // 17408 B
      #pragma unroll
      for (int m = 0; m < 4; ++m) {
        const int gm_l = wr + m * 16 + r0;                // local p-row (mult of 4)
        #pragma unroll
        for (int n = 0; n < 4; ++n) {
          const int gn_l = wc + n * 16 + ccol;            // local o-col
          const float bc = biasCol ? biasCol[n0 + gn_l] : 0.f;
          unsigned pk = pk4_fp8(acc[m][n][0] * scale + bc, acc[m][n][1] * scale + bc,
                                acc[m][n][2] * scale + bc, acc[m][n][3] * scale + bc);
          *(unsigned*)&ltb[gn_l * 136 + gm_l] = pk;       // transposed: [o][p]
        }
      }
      __syncthreads();
      unsigned char* vout = (unsigned char*)Res;          // vT8 base
      const int c0v = n0 - 1024;
      #pragma unroll
      for (int i = 0; i < 8; ++i) {
        int idx = i * 256 + tid;
        int orow = idx >> 4, pc = (idx & 15) * 8;
        unsigned long long v8 = *(const unsigned long long*)&ltb[orow * 136 + pc];
        *(unsigned long long*)&vout[(size_t)bz * sRes + (size_t)(c0v + orow) * HWP + m0 + pc] = v8;
      }
    } else {
      // ---- Q/K block: fp8 out to qk8 (ldc bytes per p-row) ----
      unsigned char* C8 = (unsigned char*)Cm;
      #pragma unroll
      for (int m = 0; m < 4; ++m) {
        const int gm = m0 + wr + m * 16 + r0;
        #pragma unroll
        for (int n = 0; n < 4; ++n) {
          const int gn = n0 + wc + n * 16 + ccol;
          const float bc = biasCol ? biasCol[gn] : 0.f;
          unsigned pk = pk4_fp8(acc[m][n][0] * scale + bc, acc[m][n][1] * scale + bc,
                                acc[m][n][2] * scale + bc, acc[m][n][3] * scale + bc);
          #pragma unroll
          for (int r = 0; r < 4; ++r)
            C8[(size_t)bz * sC + (size_t)(gm + r) * ldc + gn] =
                (unsigned char)(pk >> (8 * r));
        }
      }
    }
  } else {
    // f32 out: coalesced epilogue via LDS bounce; residual already in xr registers
    float* ft = (float*)&sm[0][0][0];
    float* Cf = (float*)Cm;
    #pragma unroll
    for (int pass = 0; pass < 2; ++pass) {
      __syncthreads();
      if ((wave >> 1) == pass) {
        #pragma unroll
        for (int m = 0; m < 4; ++m) {
          const int rl0 = m * 16 + (lane >> 4) * 4;
          #pragma unroll
          for (int n = 0; n < 4; ++n) {
            const int cl = wc + n * 16 + (lane & 15);
            #pragma unroll
            for (int r = 0; r < 4; ++r) {
              float val = acc[m][n][r];
              if (biasRow) val += biasRow[m0 + pass * 64 + rl0 + r];
              ft[(rl0 + r) * 132 + cl] = val;
            }
          }
        }
      }
      __syncthreads();
      #pragma unroll
      for (int i = 0; i < 8; ++i) {
        int idx = i * 256 + tid;
        int rrow = idx >> 5, c4 = (idx & 31) << 2;
        float4 v = *(const float4*)&ft[rrow * 132 + c4];
        const float4 rv = xr[pass * 8 + i];
        v.x += rv.x; v.y += rv.y; v.z += rv.z; v.w += rv.w;
        size_t gidx = (size_t)(m0 + pass * 64 + rrow) * ldc + (n0 + c4);
        *(float4*)&Cf[(size_t)bz * sC + gidx] = v;
      }
    }
  }
}

#define GEMM_ARGS const unsigned short* A, const unsigned short* Bm, void* Cm,            \
                  const float* biasRow, const float* biasCol, const float* Res,            \
                  int K, int lda, int ldb, int ldc, float scale,                           \
                  long long sA, long long sB, long long sC, long long sRes
#define GEMM_PASS A, Bm, Cm, biasRow, biasCol, Res, K, lda, ldb, ldc, scale, sA, sB, sC, sRes

__global__ __launch_bounds__(256) void gemm_qkv(GEMM_ARGS) { gemm_body<0>(GEMM_PASS); }
__global__ __launch_bounds__(256) void gemm_res(GEMM_ARGS) { gemm_body<3>(GEMM_PASS); }

// ================= S-GEMM fp8: 256x256-tile, BK=64, dbuf, 8 waves (2Mx4N), exp->fp8 =================
// A=q8, B=k8 (1024B rows). Wave = 128x64 output: acc[8][4]. LDS 64KB -> 2 blocks/CU.
// Per K-tile per wave: 64 MFMA, 24 ds_read_b64, 4 stage loads.
__global__ __launch_bounds__(512)
void gemm_s8(const unsigned char* __restrict__ A, const unsigned char* __restrict__ Bm,
             unsigned char* __restrict__ C,
             int K, int lda, int ldb, int ldc, float scale,
             long long sA, long long sB, long long sC) {
  const int nbx = gridDim.x, nby = gridDim.y;
  const int nb = nbx * nby * gridDim.z;
  int lin = (blockIdx.z * nby + blockIdx.y) * nbx + blockIdx.x;
  int bx, by, bz;
  if ((nb & 7) == 0) {
    int logical = (lin & 7) * (nb >> 3) + (lin >> 3);
    bx = logical % nbx;
    int t = logical / nbx;
    by = t % nby;
    bz = t / nby;
  } else { bx = blockIdx.x; by = blockIdx.y; bz = blockIdx.z; }

  const unsigned char* __restrict__ Ab = A + (size_t)bz * sA;
  const unsigned char* __restrict__ Bb = Bm + (size_t)bz * sB;
  unsigned char* __restrict__ Cb = C + (size_t)bz * sC;
  const int m0 = by * 256, n0 = bx * 256;

  __shared__ __align__(16) unsigned char smA[2][256 * 64];   // 32 KB
  __shared__ __align__(16) unsigned char smB[2][256 * 64];   // 32 KB

  const int tid = threadIdx.x, wave = tid >> 6, lane = tid & 63;
  const int wr = (wave >> 2) * 128;                 // 2 M-groups of 128
  const int wc = (wave & 3) * 64;                   // 4 N-groups of 64
  const int lr = lane & 15, lkc = lane >> 4;
  f32x4 acc[8][4] = {};

  // staging: each tensor 256x64B = 1024 16B-chunks -> 2/thread
  int sRow[2], sCol[2];
  #pragma unroll
  for (int it = 0; it < 2; ++it) {
    int chunk = it * 512 + tid;
    int row = chunk >> 2, cc = chunk & 3;
    sRow[it] = row;
    sCol[it] = ((cc ^ swz8(row)) << 4);
  }

  #define STG8(buf, kt)                                                                       \
    { _Pragma("unroll")                                                                       \
      for (int it = 0; it < 2; ++it) {                                                        \
        __builtin_amdgcn_global_load_lds(                                                     \
            (const AS1 unsigned int*)(Ab + (size_t)(m0 + sRow[it]) * lda + (kt) + sCol[it]),  \
            (AS3 unsigned int*)(&smA[buf][0] + (size_t)(it * 512 + tid) * 16), 16, 0, 0);     \
        __builtin_amdgcn_global_load_lds(                                                     \
            (const AS1 unsigned int*)(Bb + (size_t)(n0 + sRow[it]) * ldb + (kt) + sCol[it]),  \
            (AS3 unsigned int*)(&smB[buf][0] + (size_t)(it * 512 + tid) * 16), 16, 0, 0);     \
      }                                                                                       \
    }

  STG8(0, 0);
  __syncthreads();
  int cur = 0;
  for (int kt = 0; kt < K; kt += 64) {
    if (kt + 64 < K) STG8(cur ^ 1, kt + 64);
    #pragma unroll
    for (int s = 0; s < 2; ++s) {
      const int o = s * 32 + lkc * 8;
      long af[8], bfv[4];
      #pragma unroll
      for (int m = 0; m < 8; ++m) {
        int r = wr + m * 16 + lr;
        af[m] = *(const long*)&smA[cur][r * 64 + ((((o >> 4) ^ swz8(r)) << 4) | (o & 15))];
      }
      #pragma unroll
      for (int n = 0; n < 4; ++n) {
        int rb = wc + n * 16 + lr;
        bfv[n] = *(const long*)&smB[cur][rb * 64 + ((((o >> 4) ^ swz8(rb)) << 4) | (o & 15))];
      }
      #pragma unroll
      for (int m = 0; m < 8; ++m)
        #pragma unroll
        for (int n = 0; n < 4; ++n)
          acc[m][n] = __builtin_amdgcn_mfma_f32_16x16x32_fp8_fp8(af[m], bfv[n], acc[m][n], 0, 0, 0);
    }
    __syncthreads();
    cur ^= 1;
  }
  #undef STG8

  const int r0 = (lane >> 4) * 4, ccol = lane & 15;
  #pragma unroll
  for (int m = 0; m < 8; ++m) {
    const int gm = m0 + wr + m * 16 + r0;
    #pragma unroll
    for (int n = 0; n < 4; ++n) {
      const int gn = n0 + wc + n * 16 + ccol;
      unsigned pk = pk4_fp8(__expf(acc[m][n][0] * scale), __expf(acc[m][n][1] * scale),
                            __expf(acc[m][n][2] * scale), __expf(acc[m][n][3] * scale));
      #pragma unroll
      for (int r = 0; r < 4; ++r)
        Cb[(size_t)(gm + r) * ldc + gn] = (unsigned char)(pk >> (8 * r));
    }
  }
}

// ================= PV fp8: 128x256-tile, BK=64, dbuf, 8 waves, fused denominator =================
// A=P8 (4096B rows, M=4096), B=vT8 (4096B rows, N=512). BN=256 halves P8 panel re-reads.
// LDS = 2*(128+256)*64 = 48KB. 512 thr, 8 waves (2M x 4N), wave = 64x64.
__global__ __launch_bounds__(512)
void gemm_pv8(const unsigned char* __restrict__ A, const unsigned char* __restrict__ Bm,
              unsigned short* __restrict__ C,
              int K, int lda, int ldb, int ldc,
              long long sA, long long sB, long long sC) {
  const int nbx = gridDim.x, nby = gridDim.y;
  const int nb = nbx * nby * gridDim.z;
  int lin = (blockIdx.z * nby + blockIdx.y) * nbx + blockIdx.x;
  int bx, by, bz;
  if ((nb & 7) == 0) {
    int logical = (lin & 7) * (nb >> 3) + (lin >> 3);
    bx = logical % nbx;
    int t = logical / nbx;
    by = t % nby;
    bz = t / nby;
  } else { bx = blockIdx.x; by = blockIdx.y; bz = blockIdx.z; }

  const unsigned char* __restrict__ Ab = A + (size_t)bz * sA;
  const unsigned char* __restrict__ Bb = Bm + (size_t)bz * sB;
  unsigned short* __restrict__ Cb = C + (size_t)bz * sC;
  const int m0 = by * 128, n0 = bx * 256;

  __shared__ __align__(16) unsigned char pA[2][128 * 64];    // 16 KB
  __shared__ __align__(16) unsigned char pB[2][256 * 64];    // 32 KB

  const int tid = threadIdx.x, wave = tid >> 6, lane = tid & 63;
  const int wr = (wave >> 2) * 64;                  // 2 M-groups of 64
  const int wc = (wave & 3) * 64;                   // 4 N-groups of 64
  const int lr = lane & 15, lkc = lane >> 4;
  f32x4 acc[4][4] = {};
  f32x4 acc_d[4] = {};
  const long ones8 = 0x3838383838383838LL;          // 8x fp8 e4m3 1.0

  // staging: A 8KB = 512 chunks -> 1/thread; B 16KB = 1024 chunks -> 2/thread
  const int aRow = tid >> 2;
  const int aCol = (((tid & 3) ^ swz8(aRow)) << 4);
  int bRow[2], bCol[2];
  #pragma unroll
  for (int it = 0; it < 2; ++it) {
    int chunk = it * 512 + tid;
    int row = chunk >> 2, cc = chunk & 3;
    bRow[it] = row;
    bCol[it] = ((cc ^ swz8(row)) << 4);
  }

  #define STGP(buf, kt)                                                                       \
    { __builtin_amdgcn_global_load_lds(                                                       \
          (const AS1 unsigned int*)(Ab + (size_t)(m0 + aRow) * lda + (kt) + aCol),            \
          (AS3 unsigned int*)(&pA[buf][0] + (size_t)tid * 16), 16, 0, 0);                     \
      _Pragma("unroll")                                                                       \
      for (int it = 0; it < 2; ++it)                                                          \
        __builtin_amdgcn_global_load_lds(                                                     \
            (const AS1 unsigned int*)(Bb + (size_t)(n0 + bRow[it]) * ldb + (kt) + bCol[it]),  \
            (AS3 unsigned int*)(&pB[buf][0] + (size_t)(it * 512 + tid) * 16), 16, 0, 0);      \
    }

  STGP(0, 0);
  __syncthreads();
  int cur = 0;
  for (int kt = 0; kt < K; kt += 64) {
    if (kt + 64 < K) STGP(cur ^ 1, kt + 64);
    #pragma unroll
    for (int s = 0; s < 2; ++s) {
      const int o = s * 32 + lkc * 8;
      long af[4], bfv[4];
      #pragma unroll
      for (int m = 0; m < 4; ++m) {
        int r = wr + m * 16 + lr;
        af[m] = *(const long*)&pA[cur][r * 64 + ((((o >> 4) ^ swz8(r)) << 4) | (o & 15))];
      }
      #pragma unroll
      for (int n = 0; n < 4; ++n) {
        int rb = wc + n * 16 + lr;
        bfv[n] = *(const long*)&pB[cur][rb * 64 + ((((o >> 4) ^ swz8(rb)) << 4) | (o & 15))];
      }
      #pragma unroll
      for (int m = 0; m < 4; ++m) {
        #pragma unroll
        for (int n = 0; n < 4; ++n)
          acc[m][n] = __builtin_amdgcn_mfma_f32_16x16x32_fp8_fp8(af[m], bfv[n], acc[m][n], 0, 0, 0);
        acc_d[m] = __builtin_amdgcn_mfma_f32_16x16x32_fp8_fp8(af[m], ones8, acc_d[m], 0, 0, 0);
      }
    }
    __syncthreads();
    cur ^= 1;
  }
  #undef STGP

  const int r0 = (lane >> 4) * 4, ccol = lane & 15;
  #pragma unroll
  for (int m = 0; m < 4; ++m) {
    const int gm = m0 + wr + m * 16 + r0;
    const float inv0 = 1.f / acc_d[m][0];
    const float inv1 = 1.f / acc_d[m][1];
    const float inv2 = 1.f / acc_d[m][2];
    const float inv3 = 1.f / acc_d[m][3];
    #pragma unroll
    for (int n = 0; n < 4; ++n) {
      const int gn = n0 + wc + n * 16 + ccol;
      #pragma unroll
      for (int r = 0; r < 4; ++r) {
        float val = acc[m][n][r] * (r == 0 ? inv0 : r == 1 ? inv1 : r == 2 ? inv2 : inv3);
        Cb[(size_t)(gm + r) * ldc + gn] = f2bf(val);
      }
    }
  }
}

extern "C" void kernel_launch(void* const* d_in, const int* in_sizes, int n_in,
                              void* d_out, int out_size, void* d_ws, size_t ws_size,
                              hipStream_t stream) {
  (void)in_sizes; (void)n_in; (void)out_size;
  const float* x   = (const float*)d_in[0];
  const float* nsc = (const float*)d_in[1];
  const float* nbi = (const float*)d_in[2];
  const float* wq  = (const float*)d_in[3];
  const float* bq  = (const float*)d_in[4];
  const float* wk  = (const float*)d_in[5];
  const float* bk  = (const float*)d_in[6];
  const float* wv  = (const float*)d_in[7];
  const float* bv  = (const float*)d_in[8];
  const float* wp  = (const float*)d_in[9];
  const float* bp  = (const float*)d_in[10];
  float* out = (float*)d_out;
  char* ws = (char*)d_ws;

  const size_t nW = (size_t)CCH * CCH;
  unsigned short* wb = (unsigned short*)ws;            // 2 MB (bf16 weights)
  float* bcat = (float*)(ws + 4 * nW * 2);             // 6 KB
  float* stats = bcat + 1536;                          // 2 KB
  const size_t o_h = 4 * nW * 2 + 16384;
  unsigned short* ht = (unsigned short*)(ws + o_h);    // 32 MB (b, p, 512) bf16
  unsigned char* qk8 = (unsigned char*)(ht + (size_t)BATCH * HWP * CCH);   // 32 MB (b,p,1024) fp8
  unsigned char* vT8 = qk8 + (size_t)BATCH * HWP * 1024;                   // 16 MB (b,c,p) fp8
  unsigned char* P8  = vT8 + (size_t)BATCH * CCH * HWP;                    // G*16 MB (slice)
  unsigned short* ot = ht;                             // alias: ht dead after QKV gemm
  const size_t o_P8 = o_h + (size_t)BATCH * HWP * CCH * 2
                    + (size_t)BATCH * HWP * 1024 + (size_t)BATCH * CCH * HWP;
  int G = 8;
  while (G > 1 && o_P8 + (size_t)G * HWP * HWP > ws_size) G >>= 1;

  const long long sHC  = (long long)HWP * CCH;         // bf16 elements / batch
  const long long sQK8 = (long long)HWP * 1024;        // bytes / batch
  const long long sV8  = (long long)CCH * HWP;         // bytes / batch
  const long long sP8  = (long long)HWP * HWP;         // bytes / batch

  cvt_w<<<dim3((unsigned)((nW + 255) / 256)), dim3(256), 0, stream>>>(
      wq, wk, wv, wp, bq, bk, bv, wb, bcat);
  gn_stats<<<dim3(BATCH * NG), dim3(256), 0, stream>>>(x, stats);
  gn_apply<<<dim3(HWP / 64, CCH / 64, BATCH), dim3(256), 0, stream>>>(x, stats, nsc, nbi, ht);

  // fused QKV (fp8 out): Q,K -> qk8 (b,p,1024); V -> vT8 transposed (b,c,p)
  gemm_qkv<<<dim3(1536 / 128, HWP / 128, BATCH), dim3(256), 0, stream>>>(
      ht, wb, qk8, nullptr, bcat, (const float*)vT8,
      CCH, CCH, CCH, 1024, 1.f, sHC, 0, sQK8, sV8);

  const float sc = 0.04419417382415922f;               // 512^-0.5
  for (int b0 = 0; b0 < BATCH; b0 += G) {
    // P8[d][e] = fp8(exp(sc * q8[d].k8[e]))   (256x256 engine)
    gemm_s8<<<dim3(HWP / 256, HWP / 256, G), dim3(512), 0, stream>>>(
        qk8 + (size_t)b0 * sQK8, qk8 + 512 + (size_t)b0 * sQK8, P8,
        CCH, 1024, 1024, HWP, sc, sQK8, sQK8, sP8);
    // ot[d][c] = (P8[d].vT8[c]) / (P8[d].1)   (BN=256: P panels re-read 2x not 4x)
    gemm_pv8<<<dim3(CCH / 256, HWP / 128, G), dim3(512), 0, stream>>>(
        P8, vT8 + (size_t)b0 * sV8, ot + (size_t)b0 * sHC,
        HWP, HWP, HWP, CCH, sP8, sV8, sHC);
  }

  // final: out[o][p] = x[o][p] + bp[o] + sum_c wp[o][c] ot[p][c]   (bf16 engine, f32 out)
  gemm_res<<<dim3(HWP / 128, CCH / 128, BATCH), dim3(256), 0, stream>>>(
      wb + 3 * nW, ot, out, bp, nullptr, x,
      CCH, CCH, CCH, HWP, 1.f, 0, sHC, sHC, sHC);
}

// Round 23
// 453.377 us; speedup vs baseline: 1.0500x; 1.0500x over previous
//
#include <hip/hip_runtime.h>
#include <hip/hip_fp8.h>

// AttnBlock2D: GroupNorm -> fused QKV -> 1-head attention (hw=4096, dh=512) -> proj + residual
// FINAL (R23) = R21 verbatim (session best: 453.0us). R22's 256x256 S tile regressed
// (2 blocks/CU occupancy loss > MFMA density gain at K=512) and is reverted.
// vs baseline 1093us (2.41x): fused QKV GEMM + V^T in epilogue; softmax eliminated
// (exp in S epilogue, ones-MFMA denominator in PV); fp8 e4m3 attention core (HW packed
// converts with +-448 saturation); PV BN=256 for L3 re-read halving; bijective XCD
// swizzle; both-sides LDS XOR swizzles; residual register-prefetch in final projection.

#define BATCH 8
#define CCH 512
#define HWP 4096
#define NG 32

#define AS1 __attribute__((address_space(1)))
#define AS3 __attribute__((address_space(3)))

typedef __attribute__((ext_vector_type(8))) short s16x8;
typedef __attribute__((ext_vector_type(4))) float f32x4;

__device__ __forceinline__ unsigned short f2bf(float f) {
  union { float f; unsigned u; } v; v.f = f;
  return (unsigned short)((v.u + 0x7FFFu + ((v.u >> 16) & 1u)) >> 16);
}
__device__ __forceinline__ unsigned char f2fp8(float f) {
  __hip_fp8_e4m3 h(f);                               // OCP e4m3, RNE+sat (fallback path)
  return (unsigned char)h.__x;
}
// pack 4 floats -> 4 fp8 bytes (v0 in byte0); clamp to +-448 (e4m3 max) BEFORE HW convert
__device__ __forceinline__ float sat8(float v) {
  return fminf(fmaxf(v, -448.f), 448.f);
}
__device__ __forceinline__ unsigned pk4_fp8(float v0, float v1, float v2, float v3) {
#if __has_builtin(__builtin_amdgcn_cvt_pk_fp8_f32)
  int pk = __builtin_amdgcn_cvt_pk_fp8_f32(sat8(v0), sat8(v1), 0, false);   // bytes 0,1
  pk = __builtin_amdgcn_cvt_pk_fp8_f32(sat8(v2), sat8(v3), pk, true);       // bytes 2,3
  return (unsigned)pk;
#else
  return (unsigned)f2fp8(v0) | ((unsigned)f2fp8(v1) << 8) |
         ((unsigned)f2fp8(v2) << 16) | ((unsigned)f2fp8(v3) << 24);
#endif
}
__device__ __forceinline__ int swz8(int r) {         // fp8 chunk swizzle
  return (r ^ (r >> 2)) & 3;
}

// ---------------- weight convert f32 -> bf16 (4 matrices) + qkv bias concat ----------------
__global__ void cvt_w(const float* __restrict__ w0, const float* __restrict__ w1,
                      const float* __restrict__ w2, const float* __restrict__ w3,
                      const float* __restrict__ bq, const float* __restrict__ bk,
                      const float* __restrict__ bv,
                      unsigned short* __restrict__ out, float* __restrict__ bcat) {
  int i = blockIdx.x * 256 + threadIdx.x;
  const int n = CCH * CCH;
  if (i < CCH) {
    bcat[i]           = bq[i];
    bcat[CCH + i]     = bk[i];
    bcat[2 * CCH + i] = bv[i];
  }
  if (i < n) {
    out[i]         = f2bf(w0[i]);
    out[n + i]     = f2bf(w1[i]);
    out[2 * n + i] = f2bf(w2[i]);
    out[3 * n + i] = f2bf(w3[i]);
  }
}

// ---------------- GroupNorm stats: one block per (b,g) ----------------
__global__ void gn_stats(const float* __restrict__ x, float* __restrict__ stats) {
  const int bg = blockIdx.x;
  const float* base = x + (size_t)bg * (16 * HWP);
  float s = 0.f, sq = 0.f;
  for (int i = threadIdx.x; i < 16 * HWP / 4; i += 256) {
    float4 v = ((const float4*)base)[i];
    s += v.x + v.y + v.z + v.w;
    sq += v.x * v.x + v.y * v.y + v.z * v.z + v.w * v.w;
  }
  #pragma unroll
  for (int o = 32; o; o >>= 1) { s += __shfl_xor(s, o); sq += __shfl_xor(sq, o); }
  __shared__ float ls[4], lq[4];
  const int wv = threadIdx.x >> 6;
  if ((threadIdx.x & 63) == 0) { ls[wv] = s; lq[wv] = sq; }
  __syncthreads();
  if (threadIdx.x == 0) {
    s = ls[0] + ls[1] + ls[2] + ls[3];
    sq = lq[0] + lq[1] + lq[2] + lq[3];
    const float inv_n = 1.f / (16.f * HWP);
    float mean = s * inv_n;
    float var = sq * inv_n - mean * mean;
    stats[2 * bg] = mean;
    stats[2 * bg + 1] = rsqrtf(var + 1e-5f);
  }
}

// ---------------- GroupNorm apply + transpose -> h_t (hw, c) bf16 ----------------
__global__ void gn_apply(const float* __restrict__ x, const float* __restrict__ stats,
                         const float* __restrict__ scale, const float* __restrict__ bias,
                         unsigned short* __restrict__ ht) {
  const int p0 = blockIdx.x * 64, c0 = blockIdx.y * 64, b = blockIdx.z;
  const int tx = threadIdx.x & 63, ty = threadIdx.x >> 6;
  __shared__ unsigned short tile[64][65];
  #pragma unroll 4
  for (int j = 0; j < 16; ++j) {
    int cl = ty + j * 4;
    int c = c0 + cl;
    int g = c >> 4;
    float mean = stats[(b * NG + g) * 2];
    float rstd = stats[(b * NG + g) * 2 + 1];
    float v = x[((size_t)(b * CCH + c)) * HWP + p0 + tx];
    v = (v - mean) * rstd * scale[c] + bias[c];
    tile[cl][tx] = f2bf(v);
  }
  __syncthreads();
  #pragma unroll 4
  for (int j = 0; j < 16; ++j) {
    int pl = ty + j * 4;
    ht[((size_t)b * HWP + p0 + pl) * CCH + c0 + tx] = tile[tx][pl];
  }
}

// ---------------- NT GEMM (R3 engine): 128x128, BK=64, dbuf, bf16 MFMA ----------------
// MODE 0: fp8 out. n0<1024: Q/K -> qk8 (ldc=1024B rows). n0>=1024: V -> byte-LDS-bounce
//         transpose -> vT8 (=Res, stride sRes bytes).   (fused QKV + V^T, all fp8)
// MODE 3: f32 out, + biasRow + Res(prefetched to regs), coalesced epilogue (final proj)
template<int MODE>
__device__ __forceinline__ void gemm_body(
    const unsigned short* __restrict__ A, const unsigned short* __restrict__ Bm,
    void* __restrict__ Cm, const float* __restrict__ biasRow,
    const float* __restrict__ biasCol, const float* __restrict__ Res,
    int K, int lda, int ldb, int ldc, float scale,
    long long sA, long long sB, long long sC, long long sRes) {
  // --- bijective XCD swizzle ---
  const int nbx = gridDim.x, nby = gridDim.y;
  const int nb = nbx * nby * gridDim.z;
  int lin = (blockIdx.z * nby + blockIdx.y) * nbx + blockIdx.x;
  int bx, by, bz;
  if ((nb & 7) == 0) {
    int logical = (lin & 7) * (nb >> 3) + (lin >> 3);
    bx = logical % nbx;
    int t = logical / nbx;
    by = t % nby;
    bz = t / nby;
  } else { bx = blockIdx.x; by = blockIdx.y; bz = blockIdx.z; }

  const unsigned short* Ab = A + (size_t)bz * sA;
  const unsigned short* Bb = Bm + (size_t)bz * sB;
  const int m0 = by * 128, n0 = bx * 128;
  __shared__ __align__(16) unsigned short sm[2][2][128 * 64];  // [A/B][dbuf][tile]
  const int tid = threadIdx.x, wave = tid >> 6, lane = tid & 63;
  const int wr = (wave >> 1) * 64, wc = (wave & 1) * 64;
  const int lr = lane & 15, lkc = lane >> 4;
  f32x4 acc[4][4] = {};

  // MODE 3: prefetch the residual tile into registers (read hides under the K-loop)
  float4 xr[16];
  if (MODE == 3) {
    #pragma unroll
    for (int pass = 0; pass < 2; ++pass)
      #pragma unroll
      for (int i = 0; i < 8; ++i) {
        int idx = i * 256 + tid;
        int rrow = idx >> 5, c4 = (idx & 31) << 2;
        size_t gidx = (size_t)(m0 + pass * 64 + rrow) * ldc + (n0 + c4);
        xr[pass * 8 + i] = *(const float4*)&Res[(size_t)bz * sRes + gidx];
      }
  }

  const int chunkBase = wave * 64 + lane;
  int srow[4], sc8[4];
  #pragma unroll
  for (int it = 0; it < 4; ++it) {
    int chunk = it * 256 + chunkBase;
    srow[it] = chunk >> 3;
    sc8[it] = (((chunk & 7) ^ (srow[it] & 7)) * 8);
  }

  #define STAGE(buf, kt)                                                                 \
    { _Pragma("unroll")                                                                  \
      for (int it = 0; it < 4; ++it) {                                                   \
        __builtin_amdgcn_global_load_lds(                                                \
            (const AS1 unsigned int*)(Ab + (size_t)(m0 + srow[it]) * lda + (kt) + sc8[it]), \
            (AS3 unsigned int*)(&sm[0][buf][0] + (size_t)(it * 256 + wave * 64) * 8), 16, 0, 0); \
        __builtin_amdgcn_global_load_lds(                                                \
            (const AS1 unsigned int*)(Bb + (size_t)(n0 + srow[it]) * ldb + (kt) + sc8[it]), \
            (AS3 unsigned int*)(&sm[1][buf][0] + (size_t)(it * 256 + wave * 64) * 8), 16, 0, 0); \
      }                                                                                  \
    }

  STAGE(0, 0);
  __syncthreads();
  int cur = 0;
  for (int kt = 0; kt < K; kt += 64) {
    if (kt + 64 < K) STAGE(cur ^ 1, kt + 64);
    #pragma unroll
    for (int kk = 0; kk < 64; kk += 32) {
      const int jbase = (kk >> 3) + lkc;
      s16x8 af[4], bfv[4];
      #pragma unroll
      for (int m = 0; m < 4; ++m) {
        int r = wr + m * 16 + lr;
        af[m] = *(const s16x8*)&sm[0][cur][r * 64 + ((jbase ^ (r & 7)) << 3)];
      }
      #pragma unroll
      for (int n = 0; n < 4; ++n) {
        int r = wc + n * 16 + lr;
        bfv[n] = *(const s16x8*)&sm[1][cur][r * 64 + ((jbase ^ (r & 7)) << 3)];
      }
      #pragma unroll
      for (int m = 0; m < 4; ++m)
        #pragma unroll
        for (int n = 0; n < 4; ++n)
          acc[m][n] = __builtin_amdgcn_mfma_f32_16x16x32_bf16(af[m], bfv[n], acc[m][n], 0, 0, 0);
    }
    __syncthreads();
    cur ^= 1;
  }
  #undef STAGE

  const int r0 = (lane >> 4) * 4, ccol = lane & 15;
  if (MODE == 0) {
    if (n0 >= 1024) {
      // ---- V-block: fp8 transpose via byte LDS bounce [128][136] -> vT8 (b,c,p) ----
      unsigned char* ltb = (unsigned char*)&sm[0][0][0];  // 17408 B
      #pragma unroll
      for (int m = 0; m < 4; ++m) {
        const int gm_l = wr + m * 16 + r0;                // local p-row (mult of 4)
        #pragma unroll
        for (int n = 0; n < 4; ++n) {
          const int gn_l = wc + n * 16 + ccol;            // local o-col
          const float bc = biasCol ? biasCol[n0 + gn_l] : 0.f;
          unsigned pk = pk4_fp8(acc[m][n][0] * scale + bc, acc[m][n][1] * scale + bc,
                                acc[m][n][2] * scale + bc, acc[m][n][3] * scale + bc);
          *(unsigned*)&ltb[gn_l * 136 + gm_l] = pk;       // transposed: [o][p]
        }
      }
      __syncthreads();
      unsigned char* vout = (unsigned char*)Res;          // vT8 base
      const int c0v = n0 - 1024;
      #pragma unroll
      for (int i = 0; i < 8; ++i) {
        int idx = i * 256 + tid;
        int orow = idx >> 4, pc = (idx & 15) * 8;
        unsigned long long v8 = *(const unsigned long long*)&ltb[orow * 136 + pc];
        *(unsigned long long*)&vout[(size_t)bz * sRes + (size_t)(c0v + orow) * HWP + m0 + pc] = v8;
      }
    } else {
      // ---- Q/K block: fp8 out to qk8 (ldc bytes per p-row) ----
      unsigned char* C8 = (unsigned char*)Cm;
      #pragma unroll
      for (int m = 0; m < 4; ++m) {
        const int gm = m0 + wr + m * 16 + r0;
        #pragma unroll
        for (int n = 0; n < 4; ++n) {
          const int gn = n0 + wc + n * 16 + ccol;
          const float bc = biasCol ? biasCol[gn] : 0.f;
          unsigned pk = pk4_fp8(acc[m][n][0] * scale + bc, acc[m][n][1] * scale + bc,
                                acc[m][n][2] * scale + bc, acc[m][n][3] * scale + bc);
          #pragma unroll
          for (int r = 0; r < 4; ++r)
            C8[(size_t)bz * sC + (size_t)(gm + r) * ldc + gn] =
                (unsigned char)(pk >> (8 * r));
        }
      }
    }
  } else {
    // f32 out: coalesced epilogue via LDS bounce; residual already in xr registers
    float* ft = (float*)&sm[0][0][0];
    float* Cf = (float*)Cm;
    #pragma unroll
    for (int pass = 0; pass < 2; ++pass) {
      __syncthreads();
      if ((wave >> 1) == pass) {
        #pragma unroll
        for (int m = 0; m < 4; ++m) {
          const int rl0 = m * 16 + (lane >> 4) * 4;
          #pragma unroll
          for (int n = 0; n < 4; ++n) {
            const int cl = wc + n * 16 + (lane & 15);
            #pragma unroll
            for (int r = 0; r < 4; ++r) {
              float val = acc[m][n][r];
              if (biasRow) val += biasRow[m0 + pass * 64 + rl0 + r];
              ft[(rl0 + r) * 132 + cl] = val;
            }
          }
        }
      }
      __syncthreads();
      #pragma unroll
      for (int i = 0; i < 8; ++i) {
        int idx = i * 256 + tid;
        int rrow = idx >> 5, c4 = (idx & 31) << 2;
        float4 v = *(const float4*)&ft[rrow * 132 + c4];
        const float4 rv = xr[pass * 8 + i];
        v.x += rv.x; v.y += rv.y; v.z += rv.z; v.w += rv.w;
        size_t gidx = (size_t)(m0 + pass * 64 + rrow) * ldc + (n0 + c4);
        *(float4*)&Cf[(size_t)bz * sC + gidx] = v;
      }
    }
  }
}

#define GEMM_ARGS const unsigned short* A, const unsigned short* Bm, void* Cm,            \
                  const float* biasRow, const float* biasCol, const float* Res,            \
                  int K, int lda, int ldb, int ldc, float scale,                           \
                  long long sA, long long sB, long long sC, long long sRes
#define GEMM_PASS A, Bm, Cm, biasRow, biasCol, Res, K, lda, ldb, ldc, scale, sA, sB, sC, sRes

__global__ __launch_bounds__(256) void gemm_qkv(GEMM_ARGS) { gemm_body<0>(GEMM_PASS); }
__global__ __launch_bounds__(256) void gemm_res(GEMM_ARGS) { gemm_body<3>(GEMM_PASS); }

// ================= S-GEMM fp8: 256x128-tile, BK=64, dbuf, 8 waves, exp->fp8 epilogue =================
__global__ __launch_bounds__(512)
void gemm_s8(const unsigned char* __restrict__ A, const unsigned char* __restrict__ Bm,
             unsigned char* __restrict__ C,
             int K, int lda, int ldb, int ldc, float scale,
             long long sA, long long sB, long long sC) {
  const int nbx = gridDim.x, nby = gridDim.y;
  const int nb = nbx * nby * gridDim.z;
  int lin = (blockIdx.z * nby + blockIdx.y) * nbx + blockIdx.x;
  int bx, by, bz;
  if ((nb & 7) == 0) {
    int logical = (lin & 7) * (nb >> 3) + (lin >> 3);
    bx = logical % nbx;
    int t = logical / nbx;
    by = t % nby;
    bz = t / nby;
  } else { bx = blockIdx.x; by = blockIdx.y; bz = blockIdx.z; }

  const unsigned char* __restrict__ Ab = A + (size_t)bz * sA;
  const unsigned char* __restrict__ Bb = Bm + (size_t)bz * sB;
  unsigned char* __restrict__ Cb = C + (size_t)bz * sC;
  const int m0 = by * 256, n0 = bx * 128;

  __shared__ __align__(16) unsigned char smA[2][256 * 64];   // 32 KB
  __shared__ __align__(16) unsigned char smB[2][128 * 64];   // 16 KB

  const int tid = threadIdx.x, wave = tid >> 6, lane = tid & 63;
  const int wr = (wave >> 1) * 64;                  // 4 M-groups of 64
  const int wc = (wave & 1) * 64;                   // 2 N-groups of 64
  const int lr = lane & 15, lkc = lane >> 4;
  f32x4 acc[4][4] = {};

  // staging: A 16KB = 1024 16B-chunks -> 2/thread; B 512 chunks -> 1/thread
  int aRow[2], aCol[2];
  #pragma unroll
  for (int it = 0; it < 2; ++it) {
    int chunk = it * 512 + tid;
    int row = chunk >> 2, cc = chunk & 3;
    aRow[it] = row;
    aCol[it] = ((cc ^ swz8(row)) << 4);
  }
  const int bRow = tid >> 2;
  const int bCol = (((tid & 3) ^ swz8(bRow)) << 4);

  #define STG8(buf, kt)                                                                       \
    { _Pragma("unroll")                                                                       \
      for (int it = 0; it < 2; ++it)                                                          \
        __builtin_amdgcn_global_load_lds(                                                     \
            (const AS1 unsigned int*)(Ab + (size_t)(m0 + aRow[it]) * lda + (kt) + aCol[it]),  \
            (AS3 unsigned int*)(&smA[buf][0] + (size_t)(it * 512 + tid) * 16), 16, 0, 0);     \
      __builtin_amdgcn_global_load_lds(                                                       \
          (const AS1 unsigned int*)(Bb + (size_t)(n0 + bRow) * ldb + (kt) + bCol),            \
          (AS3 unsigned int*)(&smB[buf][0] + (size_t)tid * 16), 16, 0, 0);                    \
    }

  STG8(0, 0);
  __syncthreads();
  int cur = 0;
  for (int kt = 0; kt < K; kt += 64) {
    if (kt + 64 < K) STG8(cur ^ 1, kt + 64);
    #pragma unroll
    for (int s = 0; s < 2; ++s) {
      const int o = s * 32 + lkc * 8;
      long af[4], bfv[4];
      #pragma unroll
      for (int m = 0; m < 4; ++m) {
        int r = wr + m * 16 + lr;
        af[m] = *(const long*)&smA[cur][r * 64 + ((((o >> 4) ^ swz8(r)) << 4) | (o & 15))];
      }
      #pragma unroll
      for (int n = 0; n < 4; ++n) {
        int rb = wc + n * 16 + lr;
        bfv[n] = *(const long*)&smB[cur][rb * 64 + ((((o >> 4) ^ swz8(rb)) << 4) | (o & 15))];
      }
      #pragma unroll
      for (int m = 0; m < 4; ++m)
        #pragma unroll
        for (int n = 0; n < 4; ++n)
          acc[m][n] = __builtin_amdgcn_mfma_f32_16x16x32_fp8_fp8(af[m], bfv[n], acc[m][n], 0, 0, 0);
    }
    __syncthreads();
    cur ^= 1;
  }
  #undef STG8

  const int r0 = (lane >> 4) * 4, ccol = lane & 15;
  #pragma unroll
  for (int m = 0; m < 4; ++m) {
    const int gm = m0 + wr + m * 16 + r0;
    #pragma unroll
    for (int n = 0; n < 4; ++n) {
      const int gn = n0 + wc + n * 16 + ccol;
      unsigned pk = pk4_fp8(__expf(acc[m][n][0] * scale), __expf(acc[m][n][1] * scale),
                            __expf(acc[m][n][2] * scale), __expf(acc[m][n][3] * scale));
      #pragma unroll
      for (int r = 0; r < 4; ++r)
        Cb[(size_t)(gm + r) * ldc + gn] = (unsigned char)(pk >> (8 * r));
    }
  }
}

// ================= PV fp8: 128x256-tile, BK=64, dbuf, 8 waves, fused denominator =================
// A=P8 (4096B rows, M=4096), B=vT8 (4096B rows, N=512). BN=256 halves P8 panel re-reads.
// LDS = 2*(128+256)*64 = 48KB. 512 thr, 8 waves (2M x 4N), wave = 64x64.
__global__ __launch_bounds__(512)
void gemm_pv8(const unsigned char* __restrict__ A, const unsigned char* __restrict__ Bm,
              unsigned short* __restrict__ C,
              int K, int lda, int ldb, int ldc,
              long long sA, long long sB, long long sC) {
  const int nbx = gridDim.x, nby = gridDim.y;
  const int nb = nbx * nby * gridDim.z;
  int lin = (blockIdx.z * nby + blockIdx.y) * nbx + blockIdx.x;
  int bx, by, bz;
  if ((nb & 7) == 0) {
    int logical = (lin & 7) * (nb >> 3) + (lin >> 3);
    bx = logical % nbx;
    int t = logical / nbx;
    by = t % nby;
    bz = t / nby;
  } else { bx = blockIdx.x; by = blockIdx.y; bz = blockIdx.z; }

  const unsigned char* __restrict__ Ab = A + (size_t)bz * sA;
  const unsigned char* __restrict__ Bb = Bm + (size_t)bz * sB;
  unsigned short* __restrict__ Cb = C + (size_t)bz * sC;
  const int m0 = by * 128, n0 = bx * 256;

  __shared__ __align__(16) unsigned char pA[2][128 * 64];    // 16 KB
  __shared__ __align__(16) unsigned char pB[2][256 * 64];    // 32 KB

  const int tid = threadIdx.x, wave = tid >> 6, lane = tid & 63;
  const int wr = (wave >> 2) * 64;                  // 2 M-groups of 64
  const int wc = (wave & 3) * 64;                   // 4 N-groups of 64
  const int lr = lane & 15, lkc = lane >> 4;
  f32x4 acc[4][4] = {};
  f32x4 acc_d[4] = {};
  const long ones8 = 0x3838383838383838LL;          // 8x fp8 e4m3 1.0

  // staging: A 8KB = 512 chunks -> 1/thread; B 16KB = 1024 chunks -> 2/thread
  const int aRow = tid >> 2;
  const int aCol = (((tid & 3) ^ swz8(aRow)) << 4);
  int bRow[2], bCol[2];
  #pragma unroll
  for (int it = 0; it < 2; ++it) {
    int chunk = it * 512 + tid;
    int row = chunk >> 2, cc = chunk & 3;
    bRow[it] = row;
    bCol[it] = ((cc ^ swz8(row)) << 4);
  }

  #define STGP(buf, kt)                                                                       \
    { __builtin_amdgcn_global_load_lds(                                                       \
          (const AS1 unsigned int*)(Ab + (size_t)(m0 + aRow) * lda + (kt) + aCol),            \
          (AS3 unsigned int*)(&pA[buf][0] + (size_t)tid * 16), 16, 0, 0);                     \
      _Pragma("unroll")                                                                       \
      for (int it = 0; it < 2; ++it)                                                          \
        __builtin_amdgcn_global_load_lds(                                                     \
            (const AS1 unsigned int*)(Bb + (size_t)(n0 + bRow[it]) * ldb + (kt) + bCol[it]),  \
            (AS3 unsigned int*)(&pB[buf][0] + (size_t)(it * 512 + tid) * 16), 16, 0, 0);      \
    }

  STGP(0, 0);
  __syncthreads();
  int cur = 0;
  for (int kt = 0; kt < K; kt += 64) {
    if (kt + 64 < K) STGP(cur ^ 1, kt + 64);
    #pragma unroll
    for (int s = 0; s < 2; ++s) {
      const int o = s * 32 + lkc * 8;
      long af[4], bfv[4];
      #pragma unroll
      for (int m = 0; m < 4; ++m) {
        int r = wr + m * 16 + lr;
        af[m] = *(const long*)&pA[cur][r * 64 + ((((o >> 4) ^ swz8(r)) << 4) | (o & 15))];
      }
      #pragma unroll
      for (int n = 0; n < 4; ++n) {
        int rb = wc + n * 16 + lr;
        bfv[n] = *(const long*)&pB[cur][rb * 64 + ((((o >> 4) ^ swz8(rb)) << 4) | (o & 15))];
      }
      #pragma unroll
      for (int m = 0; m < 4; ++m) {
        #pragma unroll
        for (int n = 0; n < 4; ++n)
          acc[m][n] = __builtin_amdgcn_mfma_f32_16x16x32_fp8_fp8(af[m], bfv[n], acc[m][n], 0, 0, 0);
        acc_d[m] = __builtin_amdgcn_mfma_f32_16x16x32_fp8_fp8(af[m], ones8, acc_d[m], 0, 0, 0);
      }
    }
    __syncthreads();
    cur ^= 1;
  }
  #undef STGP

  const int r0 = (lane >> 4) * 4, ccol = lane & 15;
  #pragma unroll
  for (int m = 0; m < 4; ++m) {
    const int gm = m0 + wr + m * 16 + r0;
    const float inv0 = 1.f / acc_d[m][0];
    const float inv1 = 1.f / acc_d[m][1];
    const float inv2 = 1.f / acc_d[m][2];
    const float inv3 = 1.f / acc_d[m][3];
    #pragma unroll
    for (int n = 0; n < 4; ++n) {
      const int gn = n0 + wc + n * 16 + ccol;
      #pragma unroll
      for (int r = 0; r < 4; ++r) {
        float val = acc[m][n][r] * (r == 0 ? inv0 : r == 1 ? inv1 : r == 2 ? inv2 : inv3);
        Cb[(size_t)(gm + r) * ldc + gn] = f2bf(val);
      }
    }
  }
}

extern "C" void kernel_launch(void* const* d_in, const int* in_sizes, int n_in,
                              void* d_out, int out_size, void* d_ws, size_t ws_size,
                              hipStream_t stream) {
  (void)in_sizes; (void)n_in; (void)out_size;
  const float* x   = (const float*)d_in[0];
  const float* nsc = (const float*)d_in[1];
  const float* nbi = (const float*)d_in[2];
  const float* wq  = (const float*)d_in[3];
  const float* bq  = (const float*)d_in[4];
  const float* wk  = (const float*)d_in[5];
  const float* bk  = (const float*)d_in[6];
  const float* wv  = (const float*)d_in[7];
  const float* bv  = (const float*)d_in[8];
  const float* wp  = (const float*)d_in[9];
  const float* bp  = (const float*)d_in[10];
  float* out = (float*)d_out;
  char* ws = (char*)d_ws;

  const size_t nW = (size_t)CCH * CCH;
  unsigned short* wb = (unsigned short*)ws;            // 2 MB (bf16 weights)
  float* bcat = (float*)(ws + 4 * nW * 2);             // 6 KB
  float* stats = bcat + 1536;                          // 2 KB
  const size_t o_h = 4 * nW * 2 + 16384;
  unsigned short* ht = (unsigned short*)(ws + o_h);    // 32 MB (b, p, 512) bf16
  unsigned char* qk8 = (unsigned char*)(ht + (size_t)BATCH * HWP * CCH);   // 32 MB (b,p,1024) fp8
  unsigned char* vT8 = qk8 + (size_t)BATCH * HWP * 1024;                   // 16 MB (b,c,p) fp8
  unsigned char* P8  = vT8 + (size_t)BATCH * CCH * HWP;                    // G*16 MB (slice)
  unsigned short* ot = ht;                             // alias: ht dead after QKV gemm
  const size_t o_P8 = o_h + (size_t)BATCH * HWP * CCH * 2
                    + (size_t)BATCH * HWP * 1024 + (size_t)BATCH * CCH * HWP;
  int G = 8;
  while (G > 1 && o_P8 + (size_t)G * HWP * HWP > ws_size) G >>= 1;

  const long long sHC  = (long long)HWP * CCH;         // bf16 elements / batch
  const long long sQK8 = (long long)HWP * 1024;        // bytes / batch
  const long long sV8  = (long long)CCH * HWP;         // bytes / batch
  const long long sP8  = (long long)HWP * HWP;         // bytes / batch

  cvt_w<<<dim3((unsigned)((nW + 255) / 256)), dim3(256), 0, stream>>>(
      wq, wk, wv, wp, bq, bk, bv, wb, bcat);
  gn_stats<<<dim3(BATCH * NG), dim3(256), 0, stream>>>(x, stats);
  gn_apply<<<dim3(HWP / 64, CCH / 64, BATCH), dim3(256), 0, stream>>>(x, stats, nsc, nbi, ht);

  // fused QKV (fp8 out): Q,K -> qk8 (b,p,1024); V -> vT8 transposed (b,c,p)
  gemm_qkv<<<dim3(1536 / 128, HWP / 128, BATCH), dim3(256), 0, stream>>>(
      ht, wb, qk8, nullptr, bcat, (const float*)vT8,
      CCH, CCH, CCH, 1024, 1.f, sHC, 0, sQK8, sV8);

  const float sc = 0.04419417382415922f;               // 512^-0.5
  for (int b0 = 0; b0 < BATCH; b0 += G) {
    // P8[d][e] = fp8(exp(sc * q8[d].k8[e]))
    gemm_s8<<<dim3(HWP / 128, HWP / 256, G), dim3(512), 0, stream>>>(
        qk8 + (size_t)b0 * sQK8, qk8 + 512 + (size_t)b0 * sQK8, P8,
        CCH, 1024, 1024, HWP, sc, sQK8, sQK8, sP8);
    // ot[d][c] = (P8[d].vT8[c]) / (P8[d].1)   (BN=256: P panels re-read 2x not 4x)
    gemm_pv8<<<dim3(CCH / 256, HWP / 128, G), dim3(512), 0, stream>>>(
        P8, vT8 + (size_t)b0 * sV8, ot + (size_t)b0 * sHC,
        HWP, HWP, HWP, CCH, sP8, sV8, sHC);
  }

  // final: out[o][p] = x[o][p] + bp[o] + sum_c wp[o][c] ot[p][c]   (bf16 engine, f32 out)
  gemm_res<<<dim3(HWP / 128, CCH / 128, BATCH), dim3(256), 0, stream>>>(
      wb + 3 * nW, ot, out, bp, nullptr, x,
      CCH, CCH, CCH, HWP, 1.f, 0, sHC, sHC, sHC);
}